// Round 12
// baseline (414.691 us; speedup 1.0000x reference)
//
#include <hip/hip_runtime.h>

#define BDIM 1024
#define PACK_BDIM 256

typedef __attribute__((ext_vector_type(8))) short bf16x8;
typedef __attribute__((ext_vector_type(4))) float f32x4;
typedef __attribute__((ext_vector_type(4))) unsigned int u32x4;

__device__ __forceinline__ unsigned short f2b(float x) {
    unsigned u = __float_as_uint(x);
    return (unsigned short)((u + 0x7fffu + ((u >> 16) & 1u)) >> 16);
}
__device__ __forceinline__ float b2f(unsigned short b) {
    return __uint_as_float(((unsigned)b) << 16);
}

typedef __attribute__((address_space(1))) const unsigned int ga_u32;
typedef __attribute__((address_space(3))) unsigned int la_u32;
__device__ __forceinline__ void gload_lds16(const void* g, void* l) {
    __builtin_amdgcn_global_load_lds((ga_u32*)g, (la_u32*)l, 16, 0, 0);
}

// Pack 9 fp32 128x128 weights into bf16 hi/lo, SEPARATED hi/lo blocks, plus
// all 9 biases (fp32) at the end. Weight layout per gemm g (65536 B):
// s=0 hi block (32 KB), s=1 lo block (32 KB); within block chunk cf=c*8+f
// (1 KB), byte=lane*16: 8 bf16 for k=c*32+(lane>>4)*8+i, n=f*16+(lane&15).
// Bias area: floats at byte offset 589824: biasf[g*128 + col].
__global__ __launch_bounds__(PACK_BDIM) void pack_weights(
    const float* __restrict__ w0, const float* __restrict__ w1,
    const float* __restrict__ w2, const float* __restrict__ w3,
    const float* __restrict__ w4, const float* __restrict__ w5,
    const float* __restrict__ w6, const float* __restrict__ w7,
    const float* __restrict__ w8,
    const float* __restrict__ b0, const float* __restrict__ b1,
    const float* __restrict__ b2, const float* __restrict__ b3,
    const float* __restrict__ b4, const float* __restrict__ b5,
    const float* __restrict__ b6, const float* __restrict__ b7,
    const float* __restrict__ b8, unsigned short* __restrict__ wp)
{
    __shared__ float wsm[16384];
    const float* W; const float* Bp;
    switch (blockIdx.x) {
        case 0: W = w0; Bp = b0; break; case 1: W = w1; Bp = b1; break;
        case 2: W = w2; Bp = b2; break; case 3: W = w3; Bp = b3; break;
        case 4: W = w4; Bp = b4; break; case 5: W = w5; Bp = b5; break;
        case 6: W = w6; Bp = b6; break; case 7: W = w7; Bp = b7; break;
        default: W = w8; Bp = b8; break;
    }
    const int tid = threadIdx.x;
    for (int i = tid; i < 16384; i += PACK_BDIM) wsm[i] = W[i];
    float* biasf = (float*)(wp + 294912);
    if (tid < 128) biasf[blockIdx.x * 128 + tid] = Bp[tid];
    __syncthreads();
    unsigned short* dst = wp + (size_t)blockIdx.x * 32768;
    for (int item = tid; item < 4096; item += PACK_BDIM) {
        const int lane = item & 63, q = item >> 6;     // q = s*32 + c*8 + f
        const int s = q >> 5, cf = q & 31, c = cf >> 3, f = cf & 7;
        const int k0 = c * 32 + (lane >> 4) * 8;
        const int n  = f * 16 + (lane & 15);
        unsigned v2[4];
        for (int i2 = 0; i2 < 4; i2++) {
            unsigned short lohi[2];
            for (int t = 0; t < 2; t++) {
                float x = wsm[(k0 + i2 * 2 + t) * 128 + n];
                unsigned short hb = f2b(x);
                if (s) { hb = (unsigned short)(__float_as_uint(x - b2f(hb)) >> 16); }
                lohi[t] = hb;
            }
            v2[i2] = (unsigned)lohi[0] | ((unsigned)lohi[1] << 16);
        }
        u32x4 vv; vv[0] = v2[0]; vv[1] = v2[1]; vv[2] = v2[2]; vv[3] = v2[3];
        *(u32x4*)(dst + (size_t)(s * 32 + cf) * 512 + lane * 8) = vv;
    }
}

// Fused dual-input GRU cell. grid = B/64, 1024 thr = 16 waves = 4 rowgrp x
// 4 colgrp; per wave 16 rows x 32 cols -> 2-frag sets (8 regs).
// R10 lesson: 18 straight-line phases let the compiler hoist ~36 staging
// addresses + pipeline A-loads -> ~180 regs live -> massive spill at the
// 128-total cap. R11: REAL LOOP over 9 phases (runtime g from a packed
// nibble table, unroll disabled) so addresses are recomputed per iteration.
// Each phase computes standalone G = A@W + b; a switch merges G into the
// small persistent state {hx, s1, nacc} (32 acc regs). No runtime-indexed
// register arrays. Biases packed into d_ws (one base pointer).
// order u: 0 hr(6), 1 ir(0), 2 sr(3), 3 hn(8,LDS-A), 4 in(2), 5 sn(5),
//          6 hz(7), 7 iz(1), 8 sz(4).
__global__ __launch_bounds__(BDIM) __attribute__((amdgpu_waves_per_eu(4)))
void gru_fused(
    const float* __restrict__ inp, const float* __restrict__ seqp,
    const float* __restrict__ hid, const unsigned short* __restrict__ wp,
    float* __restrict__ outp)
{
    __shared__ __align__(16) unsigned short wbuf[2][16384]; // 2 x 32 KiB weights
    float* tb = (float*)wbuf[1];   // rh / output transpose overlay on buf1

    const int tid    = threadIdx.x;
    const int lane   = tid & 63;
    const int wid    = tid >> 6;       // 0..15
    const int rowgrp = wid >> 2;       // 0..3
    const int colgrp = wid & 3;        // 0..3
    const int agrp   = lane >> 4;      // 0..3
    const int a16    = lane & 15;
    const int ncol0  = colgrp * 32;
    const size_t row0 = (size_t)blockIdx.x * 64;
    const int locrow_a = rowgrp * 16 + a16;              // 0..63
    const int rswA = (locrow_a & 7) << 3;

    const float* pAin  = inp  + (row0 + locrow_a) * 128;
    const float* pAseq = seqp + (row0 + locrow_a) * 128;
    const float* pAhid = hid  + (row0 + locrow_a) * 128;
    const float* biasf = (const float*)(wp + 294912);

    f32x4 hx[2], s1[2], nacc[2], G[2];
    bf16x8 ahs[4];
    const f32x4 zv = {0.f, 0.f, 0.f, 0.f};

    auto stageu = [&](int g, int s, int b) {   // issue 32KB sub-stage, no wait
        const char* src = (const char*)wp + (size_t)g * 65536 + (size_t)s * 32768;
        char* dstb = (char*)wbuf[b];
        #pragma unroll
        for (int j = 0; j < 2; j++) {
            const int off = (j * 16 + wid) * 1024;  // wave-uniform LDS base
            gload_lds16(src + off + lane * 16, dstb + off);
        }
    };

    auto splitc = [&](int c, f32x4 x0, f32x4 x1) -> bf16x8 {
        bf16x8 al;
        #pragma unroll
        for (int i = 0; i < 4; i++) {
            unsigned u0 = __float_as_uint(x0[i]);
            ahs[c][i] = (short)(u0 >> 16);
            al[i] = (short)(__float_as_uint(x0[i] - __uint_as_float(u0 & 0xffff0000u)) >> 16);
            unsigned u1 = __float_as_uint(x1[i]);
            ahs[c][4 + i] = (short)(u1 >> 16);
            al[4 + i] = (short)(__float_as_uint(x1[i] - __uint_as_float(u1 & 0xffff0000u)) >> 16);
        }
        return al;
    };

    // G = Ah*Wh + Al*Wh (A from global, W from buf0); always re-inits G
    auto hiU = [&](const float* pA) {
        G[0] = zv; G[1] = zv;
        const unsigned short* wb = wbuf[0];
        #pragma unroll
        for (int c = 0; c < 4; c++) {
            const float* p = pA + c * 32 + agrp * 8;
            bf16x8 al = splitc(c, *(const f32x4*)(p), *(const f32x4*)(p + 4));
            #pragma unroll
            for (int f = 0; f < 2; f++) {
                const int fglob = colgrp * 2 + f;
                const bf16x8 wh = *(const bf16x8*)(&wb[(size_t)(c * 8 + fglob) * 512 + lane * 8]);
                G[f] = __builtin_amdgcn_mfma_f32_16x16x32_bf16(ahs[c], wh, G[f], 0, 0, 0);
                G[f] = __builtin_amdgcn_mfma_f32_16x16x32_bf16(al, wh, G[f], 0, 0, 0);
            }
        }
    };

    // G = Ah*Wh + Al*Wh with A rows from tb (XOR-swizzled)
    auto hiU_lds = [&]() {
        G[0] = zv; G[1] = zv;
        const unsigned short* wb = wbuf[0];
        #pragma unroll
        for (int c = 0; c < 4; c++) {
            const int rk = (c * 32 + agrp * 8) ^ rswA;
            f32x4 x0 = *(const f32x4*)(&tb[locrow_a * 128 + rk]);
            f32x4 x1 = *(const f32x4*)(&tb[locrow_a * 128 + rk + 4]);
            bf16x8 al = splitc(c, x0, x1);
            #pragma unroll
            for (int f = 0; f < 2; f++) {
                const int fglob = colgrp * 2 + f;
                const bf16x8 wh = *(const bf16x8*)(&wb[(size_t)(c * 8 + fglob) * 512 + lane * 8]);
                G[f] = __builtin_amdgcn_mfma_f32_16x16x32_bf16(ahs[c], wh, G[f], 0, 0, 0);
                G[f] = __builtin_amdgcn_mfma_f32_16x16x32_bf16(al, wh, G[f], 0, 0, 0);
            }
        }
    };

    // G += Ah*Wl (W from buf1) + bias(g)
    auto loU = [&](int g) {
        const unsigned short* wb = wbuf[1];
        #pragma unroll
        for (int c = 0; c < 4; c++)
            #pragma unroll
            for (int f = 0; f < 2; f++) {
                const int fglob = colgrp * 2 + f;
                const bf16x8 wl = *(const bf16x8*)(&wb[(size_t)(c * 8 + fglob) * 512 + lane * 8]);
                G[f] = __builtin_amdgcn_mfma_f32_16x16x32_bf16(ahs[c], wl, G[f], 0, 0, 0);
            }
        #pragma unroll
        for (int f = 0; f < 2; f++) {
            float bv = biasf[g * 128 + ncol0 + f * 16 + a16];
            #pragma unroll
            for (int j = 0; j < 4; j++) G[f][j] += bv;
        }
    };

    auto sigm = [](float x) { return 1.f / (1.f + __expf(-x)); };
    auto tanh_ = [](float x) {
        x = fminf(18.f, fmaxf(-18.f, x));
        float e = __expf(2.f * x);
        return (e - 1.f) / (e + 1.f);
    };

    const unsigned long long GT = 0x417528306ULL;  // nibble u -> gemm id
    stageu(6, 0, 0);                               // prologue: hr-Wh -> buf0

    #pragma clang loop unroll(disable)
    for (int u = 0; u < 9; ++u) {
        const int g = (int)((GT >> (4 * u)) & 15);
        if (u == 3) {
            __syncthreads();           // publishes tb(rh); hn-Wh drained into buf0
            hiU_lds();                 // reads tb (buf1) + buf0
            __syncthreads();           // all tb reads done
            stageu(g, 1, 1);           // hn-Wl -> buf1 (overwrites tb)
        } else {
            __syncthreads();           // buf1 readers done; Wh(g) drained in buf0
            stageu(g, 1, 1);           // Wl(g) -> buf1
            const float* pA = (u == 0 || u == 6) ? pAhid
                            : (u == 1 || u == 4 || u == 7) ? pAin : pAseq;
            hiU(pA);
        }
        __syncthreads();               // Wl(g) drained; buf0 readers done
        if (u < 8) stageu((int)((GT >> (4 * (u + 1))) & 15), 0, 0); // Wh(next)
        loU(g);
        // ---- merge G into persistent state ----
        switch (u) {
            case 0: case 6:
                hx[0] = G[0]; hx[1] = G[1];
                break;
            case 1: case 7:
                #pragma unroll
                for (int f = 0; f < 2; f++)
                    #pragma unroll
                    for (int j = 0; j < 4; j++)
                        s1[f][j] = sigm(G[f][j] + hx[f][j]);
                break;
            case 2: {                  // r = 0.5(s1 + sigm(G+hx)); rh -> tb
                __syncthreads();       // all waves done with loU(buf1)
                #pragma unroll
                for (int f = 0; f < 2; f++)
                    #pragma unroll
                    for (int j = 0; j < 4; j++) {
                        int row = rowgrp * 16 + agrp * 4 + j;
                        int col = ncol0 + f * 16 + a16;
                        float r = 0.5f * (s1[f][j] + sigm(G[f][j] + hx[f][j]));
                        float h = hid[(row0 + row) * 128 + col];
                        tb[row * 128 + (col ^ ((row & 7) << 3))] = r * h;
                    }
                break;
            }
            case 3:
                nacc[0] = G[0]; nacc[1] = G[1];
                break;
            case 4: case 5:
                nacc[0] += G[0]; nacc[1] += G[1];
                break;
            default:                   // u == 8: G holds sz result; fall out
                break;
        }
    }

    // ---- blend: z = 0.5(s1 + sigm(G+hx)); out = (1-z)tanh(nacc) + z*h ----
    __syncthreads();                   // last loU done; buf1/tb free
    #pragma unroll
    for (int f = 0; f < 2; f++)
        #pragma unroll
        for (int j = 0; j < 4; j++) {
            int row = rowgrp * 16 + agrp * 4 + j;
            int col = ncol0 + f * 16 + a16;
            float zz = 0.5f * (s1[f][j] + sigm(G[f][j] + hx[f][j]));
            float h  = hid[(row0 + row) * 128 + col];
            float nn = tanh_(nacc[f][j]);
            tb[row * 128 + (col ^ ((row & 7) << 3))] = (1.f - zz) * nn + zz * h;
        }
    __syncthreads();
    #pragma unroll
    for (int p = 0; p < 2; p++) {
        int e = p * 4096 + tid * 4;
        int rrow = e >> 7, c0 = e & 127;
        f32x4 v = *(const f32x4*)(&tb[rrow * 128 + (c0 ^ ((rrow & 7) << 3))]);
        *(f32x4*)(&outp[(row0 + rrow) * 128 + c0]) = v;
    }
}

extern "C" void kernel_launch(void* const* d_in, const int* in_sizes, int n_in,
                              void* d_out, int out_size, void* d_ws, size_t ws_size,
                              hipStream_t stream)
{
    (void)in_sizes; (void)n_in; (void)out_size; (void)ws_size;
    const float* inp  = (const float*)d_in[0];
    const float* seqp = (const float*)d_in[1];
    const float* hid  = (const float*)d_in[2];
    const float* W[9]; const float* Bv[9];
    for (int i = 0; i < 9; i++) {
        W[i]  = (const float*)d_in[3 + 2 * i];
        Bv[i] = (const float*)d_in[4 + 2 * i];
    }
    unsigned short* wp = (unsigned short*)d_ws; // needs 589,824 + 4,608 B

    pack_weights<<<9, PACK_BDIM, 0, stream>>>(W[0], W[1], W[2], W[3], W[4],
                                              W[5], W[6], W[7], W[8],
                                              Bv[0], Bv[1], Bv[2], Bv[3], Bv[4],
                                              Bv[5], Bv[6], Bv[7], Bv[8], wp);
    gru_fused<<<2048, BDIM, 0, stream>>>(inp, seqp, hid, wp, (float*)d_out);
}

// Round 13
// 279.214 us; speedup vs baseline: 1.4852x; 1.4852x over previous
//
#include <hip/hip_runtime.h>

#define BDIM 512
#define PACK_BDIM 256

typedef __attribute__((ext_vector_type(8))) short bf16x8;
typedef __attribute__((ext_vector_type(4))) float f32x4;
typedef __attribute__((ext_vector_type(4))) unsigned int u32x4;

__device__ __forceinline__ unsigned short f2b(float x) {
    unsigned u = __float_as_uint(x);
    return (unsigned short)((u + 0x7fffu + ((u >> 16) & 1u)) >> 16);
}
__device__ __forceinline__ float b2f(unsigned short b) {
    return __uint_as_float(((unsigned)b) << 16);
}

typedef __attribute__((address_space(1))) const unsigned int ga_u32;
typedef __attribute__((address_space(3))) unsigned int la_u32;
__device__ __forceinline__ void gload_lds16(const void* g, void* l) {
    __builtin_amdgcn_global_load_lds((ga_u32*)g, (la_u32*)l, 16, 0, 0);
}

// Pack 9 fp32 128x128 weights into bf16 hi/lo, SEPARATED hi/lo blocks, plus
// all 9 biases (fp32) at the end. Weight layout per gemm g (65536 B):
// s=0 hi block (32 KB), s=1 lo block (32 KB); within block chunk cf=c*8+f
// (1 KB), byte=lane*16: 8 bf16 for k=c*32+(lane>>4)*8+i, n=f*16+(lane&15).
// Bias area: floats at byte offset 589824: biasf[g*128 + col].
__global__ __launch_bounds__(PACK_BDIM) void pack_weights(
    const float* __restrict__ w0, const float* __restrict__ w1,
    const float* __restrict__ w2, const float* __restrict__ w3,
    const float* __restrict__ w4, const float* __restrict__ w5,
    const float* __restrict__ w6, const float* __restrict__ w7,
    const float* __restrict__ w8,
    const float* __restrict__ b0, const float* __restrict__ b1,
    const float* __restrict__ b2, const float* __restrict__ b3,
    const float* __restrict__ b4, const float* __restrict__ b5,
    const float* __restrict__ b6, const float* __restrict__ b7,
    const float* __restrict__ b8, unsigned short* __restrict__ wp)
{
    __shared__ float wsm[16384];
    const float* W; const float* Bp;
    switch (blockIdx.x) {
        case 0: W = w0; Bp = b0; break; case 1: W = w1; Bp = b1; break;
        case 2: W = w2; Bp = b2; break; case 3: W = w3; Bp = b3; break;
        case 4: W = w4; Bp = b4; break; case 5: W = w5; Bp = b5; break;
        case 6: W = w6; Bp = b6; break; case 7: W = w7; Bp = b7; break;
        default: W = w8; Bp = b8; break;
    }
    const int tid = threadIdx.x;
    for (int i = tid; i < 16384; i += PACK_BDIM) wsm[i] = W[i];
    float* biasf = (float*)(wp + 294912);
    if (tid < 128) biasf[blockIdx.x * 128 + tid] = Bp[tid];
    __syncthreads();
    unsigned short* dst = wp + (size_t)blockIdx.x * 32768;
    for (int item = tid; item < 4096; item += PACK_BDIM) {
        const int lane = item & 63, q = item >> 6;     // q = s*32 + c*8 + f
        const int s = q >> 5, cf = q & 31, c = cf >> 3, f = cf & 7;
        const int k0 = c * 32 + (lane >> 4) * 8;
        const int n  = f * 16 + (lane & 15);
        unsigned v2[4];
        for (int i2 = 0; i2 < 4; i2++) {
            unsigned short lohi[2];
            for (int t = 0; t < 2; t++) {
                float x = wsm[(k0 + i2 * 2 + t) * 128 + n];
                unsigned short hb = f2b(x);
                if (s) { hb = (unsigned short)(__float_as_uint(x - b2f(hb)) >> 16); }
                lohi[t] = hb;
            }
            v2[i2] = (unsigned)lohi[0] | ((unsigned)lohi[1] << 16);
        }
        u32x4 vv; vv[0] = v2[0]; vv[1] = v2[1]; vv[2] = v2[2]; vv[3] = v2[3];
        *(u32x4*)(dst + (size_t)(s * 32 + cf) * 512 + lane * 8) = vv;
    }
}

// Fused dual-input GRU cell. grid = B/64, 512 thr = 8 waves = 4 rowgrp x
// 2 colgrp; per wave 16 rows x 64 cols -> 4-frag sets (16 regs).
// R12 proved: the 9-phase runtime-g LOOP kills address hoisting (VGPR 56,
// zero spill) but ONE 16-wave block/CU is barrier-bound (415us). R7 proved:
// 2 co-resident 8-wave blocks overlap barrier drains (292us despite spill).
// R13 = both: loop body at 512thr/4-frag (acc 64 + arch ~40 ~= 105 < 128
// cap), LDS 2x32KB = 64KB/block -> 2 blocks/CU.
// order u: 0 hr(6), 1 ir(0), 2 sr(3), 3 hn(8,LDS-A), 4 in(2), 5 sn(5),
//          6 hz(7), 7 iz(1), 8 sz(4).
__global__ __launch_bounds__(BDIM) __attribute__((amdgpu_waves_per_eu(4)))
void gru_fused(
    const float* __restrict__ inp, const float* __restrict__ seqp,
    const float* __restrict__ hid, const unsigned short* __restrict__ wp,
    float* __restrict__ outp)
{
    __shared__ __align__(16) unsigned short wbuf[2][16384]; // 2 x 32 KiB weights
    float* tb = (float*)wbuf[1];   // rh / output transpose overlay on buf1

    const int tid    = threadIdx.x;
    const int lane   = tid & 63;
    const int wid    = tid >> 6;       // 0..7
    const int rowgrp = wid >> 1;       // 0..3
    const int colgrp = wid & 1;        // 0..1
    const int agrp   = lane >> 4;      // 0..3
    const int a16    = lane & 15;
    const int ncol0  = colgrp * 64;
    const size_t row0 = (size_t)blockIdx.x * 64;
    const int locrow_a = rowgrp * 16 + a16;              // 0..63
    const int rswA = (locrow_a & 7) << 3;

    const float* pAin  = inp  + (row0 + locrow_a) * 128;
    const float* pAseq = seqp + (row0 + locrow_a) * 128;
    const float* pAhid = hid  + (row0 + locrow_a) * 128;
    const float* biasf = (const float*)(wp + 294912);

    f32x4 hx[4], s1[4], nacc[4], G[4];
    bf16x8 ahs[4];
    const f32x4 zv = {0.f, 0.f, 0.f, 0.f};

    auto stageu = [&](int g, int s, int b) {   // issue 32KB sub-stage, no wait
        const char* src = (const char*)wp + (size_t)g * 65536 + (size_t)s * 32768;
        char* dstb = (char*)wbuf[b];
        #pragma unroll
        for (int j = 0; j < 4; j++) {
            const int off = (j * 8 + wid) * 1024;  // wave-uniform LDS base
            gload_lds16(src + off + lane * 16, dstb + off);
        }
    };

    auto splitc = [&](int c, f32x4 x0, f32x4 x1) -> bf16x8 {
        bf16x8 al;
        #pragma unroll
        for (int i = 0; i < 4; i++) {
            unsigned u0 = __float_as_uint(x0[i]);
            ahs[c][i] = (short)(u0 >> 16);
            al[i] = (short)(__float_as_uint(x0[i] - __uint_as_float(u0 & 0xffff0000u)) >> 16);
            unsigned u1 = __float_as_uint(x1[i]);
            ahs[c][4 + i] = (short)(u1 >> 16);
            al[4 + i] = (short)(__float_as_uint(x1[i] - __uint_as_float(u1 & 0xffff0000u)) >> 16);
        }
        return al;
    };

    // G = Ah*Wh + Al*Wh (A from global, W from buf0); re-inits G
    auto hiU = [&](const float* pA) {
        #pragma unroll
        for (int f = 0; f < 4; f++) G[f] = zv;
        const unsigned short* wb = wbuf[0];
        #pragma unroll
        for (int c = 0; c < 4; c++) {
            const float* p = pA + c * 32 + agrp * 8;
            bf16x8 al = splitc(c, *(const f32x4*)(p), *(const f32x4*)(p + 4));
            #pragma unroll
            for (int f = 0; f < 4; f++) {
                const int fglob = colgrp * 4 + f;
                const bf16x8 wh = *(const bf16x8*)(&wb[(size_t)(c * 8 + fglob) * 512 + lane * 8]);
                G[f] = __builtin_amdgcn_mfma_f32_16x16x32_bf16(ahs[c], wh, G[f], 0, 0, 0);
                G[f] = __builtin_amdgcn_mfma_f32_16x16x32_bf16(al, wh, G[f], 0, 0, 0);
            }
        }
    };

    // G = Ah*Wh + Al*Wh with A rows from tb (XOR-swizzled)
    auto hiU_lds = [&]() {
        #pragma unroll
        for (int f = 0; f < 4; f++) G[f] = zv;
        const unsigned short* wb = wbuf[0];
        #pragma unroll
        for (int c = 0; c < 4; c++) {
            const int rk = (c * 32 + agrp * 8) ^ rswA;
            f32x4 x0 = *(const f32x4*)(&tb[locrow_a * 128 + rk]);
            f32x4 x1 = *(const f32x4*)(&tb[locrow_a * 128 + rk + 4]);
            bf16x8 al = splitc(c, x0, x1);
            #pragma unroll
            for (int f = 0; f < 4; f++) {
                const int fglob = colgrp * 4 + f;
                const bf16x8 wh = *(const bf16x8*)(&wb[(size_t)(c * 8 + fglob) * 512 + lane * 8]);
                G[f] = __builtin_amdgcn_mfma_f32_16x16x32_bf16(ahs[c], wh, G[f], 0, 0, 0);
                G[f] = __builtin_amdgcn_mfma_f32_16x16x32_bf16(al, wh, G[f], 0, 0, 0);
            }
        }
    };

    // G += Ah*Wl (W from buf1) + bias(g)
    auto loU = [&](int g) {
        const unsigned short* wb = wbuf[1];
        #pragma unroll
        for (int c = 0; c < 4; c++)
            #pragma unroll
            for (int f = 0; f < 4; f++) {
                const int fglob = colgrp * 4 + f;
                const bf16x8 wl = *(const bf16x8*)(&wb[(size_t)(c * 8 + fglob) * 512 + lane * 8]);
                G[f] = __builtin_amdgcn_mfma_f32_16x16x32_bf16(ahs[c], wl, G[f], 0, 0, 0);
            }
        #pragma unroll
        for (int f = 0; f < 4; f++) {
            float bv = biasf[g * 128 + ncol0 + f * 16 + a16];
            #pragma unroll
            for (int j = 0; j < 4; j++) G[f][j] += bv;
        }
    };

    auto sigm = [](float x) { return 1.f / (1.f + __expf(-x)); };
    auto tanh_ = [](float x) {
        x = fminf(18.f, fmaxf(-18.f, x));
        float e = __expf(2.f * x);
        return (e - 1.f) / (e + 1.f);
    };

    const unsigned long long GT = 0x417528306ULL;  // nibble u -> gemm id
    stageu(6, 0, 0);                               // prologue: hr-Wh -> buf0

    #pragma clang loop unroll(disable)
    for (int u = 0; u < 9; ++u) {
        const int g = (int)((GT >> (4 * u)) & 15);
        if (u == 3) {
            __syncthreads();           // publishes tb(rh); hn-Wh drained into buf0
            hiU_lds();                 // reads tb (buf1) + buf0
            __syncthreads();           // all tb reads done
            stageu(g, 1, 1);           // hn-Wl -> buf1 (overwrites tb)
        } else {
            __syncthreads();           // buf1 readers done; Wh(g) drained in buf0
            stageu(g, 1, 1);           // Wl(g) -> buf1
            const float* pA = (u == 0 || u == 6) ? pAhid
                            : (u == 1 || u == 4 || u == 7) ? pAin : pAseq;
            hiU(pA);
        }
        __syncthreads();               // Wl(g) drained; buf0 readers done
        if (u < 8) stageu((int)((GT >> (4 * (u + 1))) & 15), 0, 0); // Wh(next)
        loU(g);
        // ---- merge G into persistent state ----
        switch (u) {
            case 0: case 6:
                #pragma unroll
                for (int f = 0; f < 4; f++) hx[f] = G[f];
                break;
            case 1: case 7:
                #pragma unroll
                for (int f = 0; f < 4; f++)
                    #pragma unroll
                    for (int j = 0; j < 4; j++)
                        s1[f][j] = sigm(G[f][j] + hx[f][j]);
                break;
            case 2: {                  // r = 0.5(s1 + sigm(G+hx)); rh -> tb
                __syncthreads();       // all waves done with loU(buf1)
                #pragma unroll
                for (int f = 0; f < 4; f++)
                    #pragma unroll
                    for (int j = 0; j < 4; j++) {
                        int row = rowgrp * 16 + agrp * 4 + j;
                        int col = ncol0 + f * 16 + a16;
                        float r = 0.5f * (s1[f][j] + sigm(G[f][j] + hx[f][j]));
                        float h = hid[(row0 + row) * 128 + col];
                        tb[row * 128 + (col ^ ((row & 7) << 3))] = r * h;
                    }
                break;
            }
            case 3:
                #pragma unroll
                for (int f = 0; f < 4; f++) nacc[f] = G[f];
                break;
            case 4: case 5:
                #pragma unroll
                for (int f = 0; f < 4; f++) nacc[f] += G[f];
                break;
            default:                   // u == 8: G holds sz result; fall out
                break;
        }
    }

    // ---- blend: z = 0.5(s1 + sigm(G+hx)); out = (1-z)tanh(nacc) + z*h ----
    __syncthreads();                   // last loU done; buf1/tb free
    #pragma unroll
    for (int f = 0; f < 4; f++)
        #pragma unroll
        for (int j = 0; j < 4; j++) {
            int row = rowgrp * 16 + agrp * 4 + j;
            int col = ncol0 + f * 16 + a16;
            float zz = 0.5f * (s1[f][j] + sigm(G[f][j] + hx[f][j]));
            float h  = hid[(row0 + row) * 128 + col];
            float nn = tanh_(nacc[f][j]);
            tb[row * 128 + (col ^ ((row & 7) << 3))] = (1.f - zz) * nn + zz * h;
        }
    __syncthreads();
    #pragma unroll
    for (int p = 0; p < 4; p++) {
        int e = p * 2048 + tid * 4;
        int rrow = e >> 7, c0 = e & 127;
        f32x4 v = *(const f32x4*)(&tb[rrow * 128 + (c0 ^ ((rrow & 7) << 3))]);
        *(f32x4*)(&outp[(row0 + rrow) * 128 + c0]) = v;
    }
}

extern "C" void kernel_launch(void* const* d_in, const int* in_sizes, int n_in,
                              void* d_out, int out_size, void* d_ws, size_t ws_size,
                              hipStream_t stream)
{
    (void)in_sizes; (void)n_in; (void)out_size; (void)ws_size;
    const float* inp  = (const float*)d_in[0];
    const float* seqp = (const float*)d_in[1];
    const float* hid  = (const float*)d_in[2];
    const float* W[9]; const float* Bv[9];
    for (int i = 0; i < 9; i++) {
        W[i]  = (const float*)d_in[3 + 2 * i];
        Bv[i] = (const float*)d_in[4 + 2 * i];
    }
    unsigned short* wp = (unsigned short*)d_ws; // needs 589,824 + 4,608 B

    pack_weights<<<9, PACK_BDIM, 0, stream>>>(W[0], W[1], W[2], W[3], W[4],
                                              W[5], W[6], W[7], W[8],
                                              Bv[0], Bv[1], Bv[2], Bv[3], Bv[4],
                                              Bv[5], Bv[6], Bv[7], Bv[8], wp);
    gru_fused<<<2048, BDIM, 0, stream>>>(inp, seqp, hid, wp, (float*)d_out);
}